// Round 1
// baseline (62.762 us; speedup 1.0000x reference)
//
#include <hip/hip_runtime.h>
#include <stdint.h>

namespace {

constexpr int kB = 32, kS = 8, kT = 1024, kF = 128;
constexpr int kBS = kB * kS;          // 256
constexpr int kSlice = kT * kF;       // 131072 elements per (b,s)
constexpr uint32_t kSpanT = 122;      // randint(1, 123) span
constexpr uint32_t kSpanF = 15;       // randint(1, 16)  span

struct BSParams {
  int ts1, te1, ts2, te2;   // time-mask intervals [s,e) (apply folded: e==s when not applied)
  int fs1, fe1, fs2, fe2;   // freq-mask intervals
  float scale;
  int apply_n;
  uint32_t kn0, kn1;        // noise key
};  // 48 bytes

__device__ __forceinline__ uint32_t rotl32(uint32_t v, int d) {
  return (v << d) | (v >> (32 - d));
}

// Threefry-2x32, 20 rounds (JAX-compatible).
__device__ __forceinline__ void tf2x32(uint32_t k0, uint32_t k1, uint32_t x0, uint32_t x1,
                                       uint32_t& o0, uint32_t& o1) {
  const uint32_t ks0 = k0, ks1 = k1, ks2 = k0 ^ k1 ^ 0x1BD11BDAu;
  x0 += ks0; x1 += ks1;
  // group 1 (rot 13,15,26,6)
  x0 += x1; x1 = rotl32(x1, 13); x1 ^= x0;
  x0 += x1; x1 = rotl32(x1, 15); x1 ^= x0;
  x0 += x1; x1 = rotl32(x1, 26); x1 ^= x0;
  x0 += x1; x1 = rotl32(x1, 6);  x1 ^= x0;
  x0 += ks1; x1 += ks2 + 1u;
  // group 2 (rot 17,29,16,24)
  x0 += x1; x1 = rotl32(x1, 17); x1 ^= x0;
  x0 += x1; x1 = rotl32(x1, 29); x1 ^= x0;
  x0 += x1; x1 = rotl32(x1, 16); x1 ^= x0;
  x0 += x1; x1 = rotl32(x1, 24); x1 ^= x0;
  x0 += ks2; x1 += ks0 + 2u;
  // group 3 (rot 13,15,26,6)
  x0 += x1; x1 = rotl32(x1, 13); x1 ^= x0;
  x0 += x1; x1 = rotl32(x1, 15); x1 ^= x0;
  x0 += x1; x1 = rotl32(x1, 26); x1 ^= x0;
  x0 += x1; x1 = rotl32(x1, 6);  x1 ^= x0;
  x0 += ks0; x1 += ks1 + 3u;
  // group 4 (rot 17,29,16,24)
  x0 += x1; x1 = rotl32(x1, 17); x1 ^= x0;
  x0 += x1; x1 = rotl32(x1, 29); x1 ^= x0;
  x0 += x1; x1 = rotl32(x1, 16); x1 ^= x0;
  x0 += x1; x1 = rotl32(x1, 24); x1 ^= x0;
  x0 += ks1; x1 += ks2 + 4u;
  // group 5 (rot 13,15,26,6)
  x0 += x1; x1 = rotl32(x1, 13); x1 ^= x0;
  x0 += x1; x1 = rotl32(x1, 15); x1 ^= x0;
  x0 += x1; x1 = rotl32(x1, 26); x1 ^= x0;
  x0 += x1; x1 = rotl32(x1, 6);  x1 ^= x0;
  x0 += ks2; x1 += ks0 + 5u;
  o0 = x0; o1 = x1;
}

// Partitionable-mode random bits (32-bit) at flat counter i (< 2^32): xor of both output words.
__device__ __forceinline__ uint32_t bits32(uint32_t k0, uint32_t k1, uint32_t ctr) {
  uint32_t o0, o1;
  tf2x32(k0, k1, 0u, ctr, o0, o1);
  return o0 ^ o1;
}

// uniform [0,1) from 32 random bits, JAX-style.
__device__ __forceinline__ float u01(uint32_t bits) {
  return __uint_as_float(0x3f800000u | (bits >> 9)) - 1.0f;
}

// XLA's f32 ErfInv (Giles polynomial).
__device__ __forceinline__ float erfinv_f(float x) {
  float w = -log1pf(-x * x);
  float p;
  if (w < 5.0f) {
    w -= 2.5f;
    p = 2.81022636e-08f;
    p = fmaf(p, w, 3.43273939e-07f);
    p = fmaf(p, w, -3.5233877e-06f);
    p = fmaf(p, w, -4.39150654e-06f);
    p = fmaf(p, w, 0.00021858087f);
    p = fmaf(p, w, -0.00125372503f);
    p = fmaf(p, w, -0.00417768164f);
    p = fmaf(p, w, 0.246640727f);
    p = fmaf(p, w, 1.50140941f);
  } else {
    w = sqrtf(w) - 3.0f;
    p = -0.000200214257f;
    p = fmaf(p, w, 0.000100950558f);
    p = fmaf(p, w, 0.00134934322f);
    p = fmaf(p, w, -0.00367342844f);
    p = fmaf(p, w, 0.00573950773f);
    p = fmaf(p, w, -0.0076224613f);
    p = fmaf(p, w, 0.00943887047f);
    p = fmaf(p, w, 1.00167406f);
    p = fmaf(p, w, 2.83297682f);
  }
  return p * x;
}

// One _axis_mask's per-(b,s) params: split(K,3) -> k1(randint),k2(uniform start),k3(apply).
__device__ void axis_params(uint32_t K0, uint32_t K1, int dim, uint32_t span, uint32_t i,
                            int& start_out, int& end_out) {
  uint32_t k10, k11, k20, k21, k30, k31, a0, a1, b0, b1;
  tf2x32(K0, K1, 0u, 0u, k10, k11);   // k1
  tf2x32(K0, K1, 0u, 1u, k20, k21);   // k2
  tf2x32(K0, K1, 0u, 2u, k30, k31);   // k3
  // randint(k1, (B,S), 1, span+1): internal split(k1) -> two bit streams
  tf2x32(k10, k11, 0u, 0u, a0, a1);
  tf2x32(k10, k11, 0u, 1u, b0, b1);
  uint32_t hi = bits32(a0, a1, i);
  uint32_t lo = bits32(b0, b1, i);
  uint32_t mult = 65536u % span;
  mult = (mult * mult) % span;
  uint32_t off = ((hi % span) * mult + (lo % span)) % span;
  int width = 1 + (int)off;
  float u = u01(bits32(k20, k21, i));
  int M = dim - width; if (M < 1) M = 1;
  int start = (int)floorf(u * (float)M);
  bool apply = u01(bits32(k30, k31, i)) > 0.35f;
  start_out = start;
  end_out = apply ? (start + width) : start;   // empty interval when not applied
}

__device__ BSParams compute_params(uint32_t i) {
  BSParams p;
  uint32_t w0, w1;
  // key(42) = (0,42); split(key,8) fold-like: subkey j = TF(key; 0, j)
  tf2x32(0u, 42u, 0u, 0u, w0, w1); axis_params(w0, w1, kT, kSpanT, i, p.ts1, p.te1);  // kt1
  tf2x32(0u, 42u, 0u, 1u, w0, w1); axis_params(w0, w1, kT, kSpanT, i, p.ts2, p.te2);  // kt2
  tf2x32(0u, 42u, 0u, 2u, w0, w1); axis_params(w0, w1, kF, kSpanF, i, p.fs1, p.fe1);  // kf1
  tf2x32(0u, 42u, 0u, 3u, w0, w1); axis_params(w0, w1, kF, kSpanF, i, p.fs2, p.fe2);  // kf2
  tf2x32(0u, 42u, 0u, 4u, w0, w1);                                                    // kn_a
  p.apply_n = (u01(bits32(w0, w1, i)) > 0.45f) ? 1 : 0;
  tf2x32(0u, 42u, 0u, 5u, p.kn0, p.kn1);                                              // kn
  tf2x32(0u, 42u, 0u, 6u, w0, w1);                                                    // ks_a
  bool apply_s = u01(bits32(w0, w1, i)) > 0.5f;
  tf2x32(0u, 42u, 0u, 7u, w0, w1);                                                    // ks
  float su = u01(bits32(w0, w1, i));
  float sc = fmaxf(0.85f, fmaf(su, 1.15f - 0.85f, 0.85f));
  p.scale = apply_s ? sc : 1.0f;
  return p;
}

__global__ void spec_params_kernel(BSParams* __restrict__ P) {
  uint32_t i = threadIdx.x;  // 0..255 == b*8+s
  P[i] = compute_params(i);
}

template <bool USE_WS>
__global__ __launch_bounds__(256) void spec_main_kernel(const float* __restrict__ specs,
                                                        const int* __restrict__ mask,
                                                        float* __restrict__ out,
                                                        const BSParams* __restrict__ P) {
  const int bs = blockIdx.y;                      // 0..255
  const int off = blockIdx.x * 2048 + threadIdx.x * 8;  // element offset within slice
  const long base = (long)bs * kSlice + off;
  const float4* in4 = reinterpret_cast<const float4*>(specs + base);
  float4 a = in4[0];
  float4 b = in4[1];
  float4* out4 = reinterpret_cast<float4*>(out + base);

  const bool on = (mask[bs] != 0);
  if (!on) {  // sensor off: pure passthrough (uniform per block)
    out4[0] = a; out4[1] = b;
    return;
  }

  BSParams p;
  if (USE_WS) p = P[bs]; else p = compute_params((uint32_t)bs);

  const int t = off >> 7;        // all 8 elems share t (8 | 128)
  const int f0 = off & 127;
  const bool tm = !((t >= p.ts1) & (t < p.te1)) && !((t >= p.ts2) & (t < p.te2));

  const float LO = __int_as_float(0xBF7FFFFF);   // nextafter(-1, 0)
  float v[8] = {a.x, a.y, a.z, a.w, b.x, b.y, b.z, b.w};

  if (p.apply_n) {   // uniform per block
#pragma unroll
    for (int j = 0; j < 8; ++j) {
      const int f = f0 + j;
      const bool fm = !((f >= p.fs1) & (f < p.fe1)) && !((f >= p.fs2) & (f < p.fe2));
      float s = (tm && fm) ? v[j] : 0.0f;
      const uint32_t bits = bits32(p.kn0, p.kn1, (uint32_t)(base + j));
      float x = fmaxf(LO, u01(bits) * 2.0f + LO);
      s += 0.06f * (1.41421356f * erfinv_f(x));
      s *= p.scale;
      v[j] = fminf(10.0f, fmaxf(-10.0f, s));
    }
  } else {
#pragma unroll
    for (int j = 0; j < 8; ++j) {
      const int f = f0 + j;
      const bool fm = !((f >= p.fs1) & (f < p.fe1)) && !((f >= p.fs2) & (f < p.fe2));
      float s = (tm && fm) ? v[j] : 0.0f;
      s *= p.scale;
      v[j] = fminf(10.0f, fmaxf(-10.0f, s));
    }
  }

  out4[0] = make_float4(v[0], v[1], v[2], v[3]);
  out4[1] = make_float4(v[4], v[5], v[6], v[7]);
}

}  // namespace

extern "C" void kernel_launch(void* const* d_in, const int* in_sizes, int n_in,
                              void* d_out, int out_size, void* d_ws, size_t ws_size,
                              hipStream_t stream) {
  const float* specs = (const float*)d_in[0];
  const int* mask = (const int*)d_in[1];
  float* out = (float*)d_out;

  dim3 grid(kSlice / 2048, kBS);  // (64, 256)
  dim3 block(256);

  if (ws_size >= sizeof(BSParams) * kBS) {
    BSParams* P = (BSParams*)d_ws;
    hipLaunchKernelGGL(spec_params_kernel, dim3(1), dim3(kBS), 0, stream, P);
    hipLaunchKernelGGL((spec_main_kernel<true>), grid, block, 0, stream, specs, mask, out, P);
  } else {
    hipLaunchKernelGGL((spec_main_kernel<false>), grid, block, 0, stream, specs, mask, out,
                       (const BSParams*)nullptr);
  }
}